// Round 9
// baseline (556.522 us; speedup 1.0000x reference)
//
#include <hip/hip_runtime.h>
#include <stdint.h>

// SpikingLinearLayer: spikes = LIF_scan(x @ W^T)  -- exact i8-limb MFMA path.
//   x: [20, 1024, 2048] fp32 binary; W: [2048, 2048] fp32; out fp32 binary.
//
// R12 -> R13: amortize the fixed region quantum. KC 128 -> 256.
//  * R12 confirmed bit-packed A + BM=256/BO=16/TT=4 retile: 445 -> 305us,
//    MfmaUtil 48%, FETCH 29MB (all operands L2/L3-resident).
//  * Refined model (R4/R11/R12): region = MFMA_issue + ~2000 cyc FIXED
//    overhead, independent of staged bytes (48/32/24KB -> 2369/2033/1964).
//    It's the __syncthreads drain+barrier quantum, not fetch BW. So halve
//    the region count: KC2=256, NITER 40/block (80 execs/CU) -> saves
//    ~80 x 2000 cyc ~ 67us. Staged 48KB still < the 5222-cyc MFMA window.
//  * NOT R9's failure: that KC=256 regression was HBM blowup in the
//    1B/elem-A era (FETCH 406MB); now FETCH=29MB, fully cached.
//  * Sync unchanged (replay-proven): all staging via global_load_lds, ONE
//    __syncthreads()/region, no inline asm, no setprio. Math byte-identical.
//  * LDS 2 x 48KB = 96KB -> 1 resident block/CU (blocks already serialized
//    by the 248-combined-reg budget; no occupancy change).

constexpr int T_STEPS = 20;
constexpr int BATCH   = 1024;
constexpr int NIN     = 2048;
constexpr int NOUT    = 2048;

constexpr int    Q         = 4;
constexpr double SCALE     = 1073741824.0;     // 2^30
constexpr double INV_SCALE = 1.0 / SCALE;

// packed x: [t][g128(16)][b(1024)][16B]  (16B = 128 k-bits)
constexpr size_t XIP_BYTES   = (size_t)T_STEPS * 16 * 1024 * 16;     // 5 MB
constexpr size_t PLANE_BYTES = (size_t)NOUT * NIN;                   // 4 MB
constexpr size_t WS_NEEDED   = XIP_BYTES + (size_t)Q * PLANE_BYTES;  // 21 MB

typedef int v4i __attribute__((ext_vector_type(4)));

// async 16B/lane global->LDS DMA: lds dst = uniform base + lane*16
__device__ __forceinline__ void dma16(const int8_t* g, const int8_t* l) {
    __builtin_amdgcn_global_load_lds(
        (const __attribute__((address_space(1))) void*)(uintptr_t)g,
        (__attribute__((address_space(3))) void*)(uint32_t)(uintptr_t)l,
        16, 0, 0);
}

// 16 bits -> 16 bytes {0,1} (4 dwords), little-endian k-ascending
__device__ __forceinline__ v4i expand16(uint32_t b) {
    v4i r;
    r[0] = (int)((((b      ) & 0xFu) * 0x00204081u) & 0x01010101u);
    r[1] = (int)((((b >>  4) & 0xFu) * 0x00204081u) & 0x01010101u);
    r[2] = (int)((((b >>  8) & 0xFu) * 0x00204081u) & 0x01010101u);
    r[3] = (int)((((b >> 12) & 0xFu) * 0x00204081u) & 0x01010101u);
    return r;
}

// ------------------------------------------- prep: x -> packed bits (ballot)
// one wave per (t,b) row; 32 ballots of 64 consecutive k each.
__global__ void prep_x(const float* __restrict__ x, int8_t* __restrict__ xp) {
    const int tid  = threadIdx.x;
    const int ln   = tid & 63;
    const int row  = blockIdx.x * 4 + (tid >> 6);        // 20480 rows
    const int t    = row >> 10;
    const int b    = row & 1023;
    const float* xr = x + (size_t)row * NIN;
#pragma unroll
    for (int c = 0; c < 32; ++c) {                       // k = c*64 + ln
        const unsigned long long m = __ballot(xr[c * 64 + ln] != 0.0f);
        if (ln == 0)
            *reinterpret_cast<unsigned long long*>(
                xp + (((size_t)t * 16 + (c >> 1)) * 1024 + b) * 16
                   + (c & 1) * 8) = m;
    }
}

// ------------------------------------------------- prep: W -> 4 base-256 digits
__global__ void prep_limbs(const float* __restrict__ w, int8_t* __restrict__ limbs) {
    const int idx = blockIdx.x * blockDim.x + threadIdx.x;   // 4 weights each
    const float4 wv = reinterpret_cast<const float4*>(w)[idx];
    const float wf[4] = {wv.x, wv.y, wv.z, wv.w};
    int8_t d[Q][4];
#pragma unroll
    for (int e = 0; e < 4; ++e) {
        long long M = llrint((double)wf[e] * SCALE);         // |M| < 2^30
#pragma unroll
        for (int j = 0; j < Q - 1; ++j) {
            const int dj = (int)((M + 128) & 255) - 128;
            d[j][e] = (int8_t)dj;
            M = (M - dj) >> 8;                               // exact
        }
        d[Q - 1][e] = (int8_t)M;                             // |top| <= 65
    }
#pragma unroll
    for (int j = 0; j < Q; ++j)
        reinterpret_cast<char4*>(limbs + (size_t)j * PLANE_BYTES)[idx] =
            make_char4(d[j][0], d[j][1], d[j][2], d[j][3]);
}

// --------------------------------------------------------------- hot: i8 GEMMs
constexpr int KC2    = 256;                 // K per region (4 x 64 sub-chunks)
constexpr int NKC2   = NIN / KC2;           // 8
constexpr int TT     = 4;                   // timesteps per sweep
constexpr int NTQ    = T_STEPS / TT;        // 5 t-quads
constexpr int NITER  = NTQ * NKC2;          // 40 regions per block
constexpr int BM     = 256;                 // batch tile (16 rg of 16)
constexpr int BO     = 16;                  // out tile (1 o-group)
constexpr int B_OFF  = 32768;               // A: 32KB packed-bits; B: 16KB i8
constexpr int BUF_B  = 49152;

__global__ __launch_bounds__(512, 2)
void snn_i8(const int8_t* __restrict__ xp, const int8_t* __restrict__ limbs,
            float* __restrict__ out)
{
    // XCD swizzle: 16 o-tiles per XCD -> B slice 2MB in L2; A-packed 5MB in L3
    const int bid   = blockIdx.x;            // 512 blocks
    const int xcd   = bid & 7;
    const int sub   = bid >> 3;              // 0..63
    const int otile = xcd * 16 + (sub & 15); // 0..127
    const int btile = sub >> 4;              // 0..3
    const int o0 = otile * BO, b0 = btile * BM;

    const int tid = threadIdx.x;
    const int w   = tid >> 6;                // wave 0..7: owns rows 32w..32w+31
    const int ln  = tid & 63;
    const int lm  = ln & 15;
    const int qd  = ln >> 4;

    __shared__ __align__(16) int8_t lds[2][BUF_B];   // 96 KB

    // staging assignment (6 dma16/wave/region):
    const int sa_tt = w >> 1;                // A t-step (0..3)
    const int sa_h  = w & 1;                 // A k-half (128 bits each)
    const int sb_j  = w >> 1;                // B limb plane
    const int sb_kq = w & 1;                 // B k-quarter-pair (128 B)

    // B source (per-lane): plane sb_j, row o0+lm, k-byte base + c*64 + qd*16
    const size_t b_src = (size_t)sb_j * PLANE_BYTES
                       + (size_t)(o0 + lm) * NIN + sb_kq * 128 + qd * 16;

    // LIF state: e = rg2*4+r -> b = b0+(2w+rg2)*16+4qd+r, o = o0+lm
    double V[8], I[8];
#pragma unroll
    for (int e = 0; e < 8; ++e) { V[e] = 0.0; I[e] = 0.0; }

    const double alpha_m = 1.0 - 1.0 / 20.0;
    const double alpha_s = 1.0 - 1.0 / 5.0;
    const double dtm     = 1.0 / 20.0;

    // stage region s into lds[s&1]:
    //   A: 4 dma (row-chunks g of 64) of packed group 2*kc2+sa_h, t=sa_tt
    //      dst = sa_tt*8192 + sa_h*4096 + (g*64+ln)*16
    //   B: 2 dma (c=0,1) of plane sb_j k-bytes [kc2*256+sb_kq*128+c*64 ..)
    //      dst = B_OFF + (sb_j*4 + sb_kq*2 + c)*1024 + ln*16
    auto stage = [&](int s) {
        const int tq  = s >> 3;
        const int kc2 = s & 7;
        int8_t* lb = &lds[s & 1][0];
        const int8_t* asrc = xp
            + (((size_t)(tq * 4 + sa_tt) * 16 + (2 * kc2 + sa_h)) * 1024
               + b0) * 16;
#pragma unroll
        for (int g = 0; g < 4; ++g)
            dma16(asrc + (size_t)(g * 64 + ln) * 16,
                  lb + sa_tt * 8192 + sa_h * 4096 + g * 1024);
#pragma unroll
        for (int c = 0; c < 2; ++c)
            dma16(limbs + b_src + (size_t)kc2 * KC2 + c * 64,
                  lb + B_OFF + (sb_j * 4 + sb_kq * 2 + c) * 1024);
    };

    stage(0);
    __syncthreads();

    int s = 0;
    for (int tq = 0; tq < NTQ; ++tq) {
        v4i acc[2][4][4];   // [rg2][tt][plane]
#pragma unroll
        for (int rg2 = 0; rg2 < 2; ++rg2)
#pragma unroll
            for (int tt = 0; tt < TT; ++tt)
#pragma unroll
                for (int j = 0; j < Q; ++j)
                    acc[rg2][tt][j] = (v4i){0, 0, 0, 0};

        for (int kci = 0; kci < NKC2; ++kci, ++s) {
            if (s + 1 < NITER) stage(s + 1);            // async prefetch

            const int8_t* cb = &lds[s & 1][0];
#pragma unroll
            for (int s2 = 0; s2 < 4; ++s2) {            // four K=64 sub-chunks
                v4i B[4];
#pragma unroll
                for (int j = 0; j < Q; ++j)
                    B[j] = *reinterpret_cast<const v4i*>(
                        cb + B_OFF + (j * 4 + s2) * 1024 + ln * 16);
#pragma unroll
                for (int rg2 = 0; rg2 < 2; ++rg2) {
                    const int r = (2 * w + rg2) * 16 + lm;
#pragma unroll
                    for (int tt = 0; tt < TT; ++tt) {
                        const uint32_t bits =
                            *reinterpret_cast<const uint16_t*>(
                                cb + tt * 8192 + (s2 >> 1) * 4096 + r * 16
                                   + (s2 & 1) * 8 + qd * 2);
                        const v4i A = expand16(bits);
#pragma unroll
                        for (int j = 0; j < Q; ++j)
                            acc[rg2][tt][j] =
                                __builtin_amdgcn_mfma_i32_16x16x64_i8(
                                    A, B[j], acc[rg2][tt][j], 0, 0, 0);
                    }
                }
            }
            __syncthreads();   // drains DMA (landed under 256 MFMAs)
        }

        // recombine digits (exact fp64), LIF, emit spikes for t-quad
        const int ocol = o0 + lm;
#pragma unroll
        for (int rg2 = 0; rg2 < 2; ++rg2) {
#pragma unroll
            for (int r = 0; r < 4; ++r) {
                const int e = rg2 * 4 + r;
                const int brow = b0 + (2 * w + rg2) * 16 + 4 * qd + r;
#pragma unroll
                for (int tt = 0; tt < TT; ++tt) {
                    const int d0 = acc[rg2][tt][0][r];
                    const int d1 = acc[rg2][tt][1][r];
                    const int d2 = acc[rg2][tt][2][r];
                    const int d3 = acc[rg2][tt][3][r];
                    double sm = (double)d3;
                    sm = sm * 256.0 + (double)d2;
                    sm = sm * 256.0 + (double)d1;
                    sm = sm * 256.0 + (double)d0;
                    const double cur = sm * INV_SCALE;

                    I[e] = alpha_s * I[e] + cur;
                    V[e] = alpha_m * V[e] + dtm * I[e];
                    const double sp = (V[e] >= 1.0) ? 1.0 : 0.0;
                    V[e] *= (1.0 - sp);

                    __builtin_nontemporal_store(
                        (float)sp,
                        out + (size_t)(tq * 4 + tt) * BATCH * NOUT
                            + (size_t)brow * NOUT + ocol);
                }
            }
        }
    }
}

// ------------------------------------------------ fallback: verified R1 kernel
constexpr int TBF = 64, TOF = 64, KCF = 64, LDPF = KCF + 4;

__global__ __launch_bounds__(256, 2)
void snn_fused(const float* __restrict__ x,
               const float* __restrict__ w,
               float* __restrict__ out)
{
    const int o0  = blockIdx.x * TOF;
    const int b0  = blockIdx.y * TBF;
    const int tid = threadIdx.x;
    const int tx  = tid & 15;
    const int ty  = tid >> 4;

    __shared__ float xs[TBF][LDPF];
    __shared__ float ws[TOF][LDPF];

    const int lr = tid >> 2;
    const int lc = (tid & 3) << 4;

    double V[4][4], I[4][4];
#pragma unroll
    for (int i = 0; i < 4; ++i)
#pragma unroll
        for (int j = 0; j < 4; ++j) { V[i][j] = 0.0; I[i][j] = 0.0; }

    const double alpha_m = 1.0 - 1.0 / 20.0;
    const double alpha_s = 1.0 - 1.0 / 5.0;
    const double dtm     = 1.0 / 20.0;

    for (int t = 0; t < T_STEPS; ++t) {
        const float* xt = x + (size_t)t * BATCH * NIN;
        double c[4][4];
#pragma unroll
        for (int i = 0; i < 4; ++i)
#pragma unroll
            for (int j = 0; j < 4; ++j) c[i][j] = 0.0;

        for (int kc = 0; kc < NIN; kc += KCF) {
            __syncthreads();
            {
                const float4* xg = reinterpret_cast<const float4*>(
                    xt + (size_t)(b0 + lr) * NIN + kc + lc);
                const float4* wg = reinterpret_cast<const float4*>(
                    w + (size_t)(o0 + lr) * NIN + kc + lc);
#pragma unroll
                for (int q = 0; q < 4; ++q) {
                    float4 xv = xg[q];
                    float4 wv4 = wg[q];
                    const int cbi = lc + q * 4;
                    xs[lr][cbi + 0] = xv.x;  xs[lr][cbi + 1] = xv.y;
                    xs[lr][cbi + 2] = xv.z;  xs[lr][cbi + 3] = xv.w;
                    ws[lr][cbi + 0] = wv4.x; ws[lr][cbi + 1] = wv4.y;
                    ws[lr][cbi + 2] = wv4.z; ws[lr][cbi + 3] = wv4.w;
                }
            }
            __syncthreads();

#pragma unroll 8
            for (int k = 0; k < KCF; ++k) {
                float xa[4], wa[4];
#pragma unroll
                for (int i = 0; i < 4; ++i) xa[i] = xs[ty * 4 + i][k];
#pragma unroll
                for (int j = 0; j < 4; ++j) wa[j] = ws[tx * 4 + j][k];
#pragma unroll
                for (int i = 0; i < 4; ++i)
#pragma unroll
                    for (int j = 0; j < 4; ++j)
                        c[i][j] += (double)xa[i] * (double)wa[j];
            }
        }

#pragma unroll
        for (int i = 0; i < 4; ++i) {
            float sv[4];
#pragma unroll
            for (int j = 0; j < 4; ++j) {
                I[i][j] = alpha_s * I[i][j] + c[i][j];
                V[i][j] = alpha_m * V[i][j] + dtm * I[i][j];
                const double sp = (V[i][j] >= 1.0) ? 1.0 : 0.0;
                V[i][j] *= (1.0 - sp);
                sv[j] = (float)sp;
            }
            const size_t oidx = (size_t)t * BATCH * NOUT
                              + (size_t)(b0 + ty * 4 + i) * NOUT
                              + (size_t)(o0 + tx * 4);
            *reinterpret_cast<float4*>(out + oidx) =
                make_float4(sv[0], sv[1], sv[2], sv[3]);
        }
    }
}

extern "C" void kernel_launch(void* const* d_in, const int* in_sizes, int n_in,
                              void* d_out, int out_size, void* d_ws, size_t ws_size,
                              hipStream_t stream) {
    const float* x = (const float*)d_in[0];
    const float* w = (const float*)d_in[1];
    float* out     = (float*)d_out;
    (void)in_sizes; (void)n_in; (void)out_size;

    if (ws_size >= WS_NEEDED) {
        int8_t* xp    = (int8_t*)d_ws;
        int8_t* limbs = xp + XIP_BYTES;
        prep_x<<<5120, 256, 0, stream>>>(x, xp);
        prep_limbs<<<(int)(PLANE_BYTES / 4 / 256), 256, 0, stream>>>(w, limbs);
        snn_i8<<<512, 512, 0, stream>>>(xp, limbs, out);
    } else {
        dim3 grid(NOUT / TOF, BATCH / TBF);
        snn_fused<<<grid, dim3(256), 0, stream>>>(x, w, out);
    }
}